// Round 4
// baseline (152.345 us; speedup 1.0000x reference)
//
#include <hip/hip_runtime.h>

typedef __attribute__((ext_vector_type(8))) short short8;
typedef __attribute__((ext_vector_type(4))) float f32x4;
typedef __attribute__((ext_vector_type(16))) float f32x16;

#define DEV __device__ __forceinline__

constexpr int Bb = 2, Ss = 2048, Tt = 2048, Ee = 1024, Hh = 16, HDd = 64;
constexpr int Mm = Bb * Ss;                  // 4096 tokens
constexpr size_t NX = (size_t)Mm * Ee;       // 4194304 elems (also mask count)
constexpr size_t NW = (size_t)Ee * Ee;       // 1048576 elems

// ---- workspace layout (bytes) ----
constexpr size_t OFF_XQ   = 0;
constexpr size_t OFF_XK   = OFF_XQ + NX * 2;
constexpr size_t OFF_XV   = OFF_XK + NX * 2;
constexpr size_t OFF_WQ   = OFF_XV + NX * 2;
constexpr size_t OFF_WK   = OFF_WQ + NW * 2;
constexpr size_t OFF_WV   = OFF_WK + NW * 2;
constexpr size_t OFF_WO   = OFF_WV + NW * 2;
constexpr size_t OFF_QH   = OFF_WO + NW * 2;   // [B*H][S][64] bf16
constexpr size_t OFF_KH   = OFF_QH + NX * 2;
constexpr size_t OFF_VH   = OFF_KH + NX * 2;
constexpr size_t OFF_OB   = OFF_VH + NX * 2;   // [B][S][E] bf16 attention out
constexpr size_t OFF_FLAG = OFF_OB + NX * 2;   // int: 1 if mask has a zero

DEV unsigned short f2bf(float f) {
  union { float f; unsigned u; } v; v.f = f;
  unsigned r = v.u + 0x7fffu + ((v.u >> 16) & 1u);   // RNE
  return (unsigned short)(r >> 16);
}

#define GLDS16(g, l) __builtin_amdgcn_global_load_lds(                         \
    (const __attribute__((address_space(1))) void*)(g),                        \
    (__attribute__((address_space(3))) void*)(l), 16, 0, 0)

// swap hi-half of a with lo-half of b. ONLY safe when a,b are distinct live
// SSA values (identical copies get register-coalesced -> self-swap bug!).
#define PLSWAP(a, b) asm("v_permlane32_swap_b32 %0, %1" : "+v"(a), "+v"(b))
#define CVTPK(d, lo, hi_) asm("v_cvt_pk_bf16_f32 %0, %1, %2" : "=v"(d) : "v"(lo), "v"(hi_))

#if __has_builtin(__builtin_amdgcn_exp2f)
#define EXP2(x) __builtin_amdgcn_exp2f(x)
#else
#define EXP2(x) exp2f(x)
#endif

// ============ prep: f32 -> bf16 converts + mask scan ============
__global__ __launch_bounds__(256) void prep_kernel(
    const float* __restrict__ q, const float* __restrict__ k, const float* __restrict__ v,
    const float* __restrict__ wq, const float* __restrict__ wk,
    const float* __restrict__ wv, const float* __restrict__ wo,
    const int* __restrict__ mask,
    unsigned short* __restrict__ Xq, unsigned short* __restrict__ Xk, unsigned short* __restrict__ Xv,
    unsigned short* __restrict__ Wqb, unsigned short* __restrict__ Wkb,
    unsigned short* __restrict__ Wvb, unsigned short* __restrict__ Wob,
    int* __restrict__ flagZero)
{
  constexpr size_t NXv = NX / 4, NWv = NW / 4;
  constexpr size_t tot = 4 * NXv + 4 * NWv;
  for (size_t u = (size_t)blockIdx.x * blockDim.x + threadIdx.x; u < tot;
       u += (size_t)gridDim.x * blockDim.x) {
    if (u < 3 * NXv) {
      const float* src; unsigned short* dst; size_t off;
      if (u < NXv)            { src = q; dst = Xq; off = u; }
      else if (u < 2 * NXv)   { src = k; dst = Xk; off = u - NXv; }
      else                    { src = v; dst = Xv; off = u - 2 * NXv; }
      float4 f = ((const float4*)src)[off];
      ushort4 o; o.x = f2bf(f.x); o.y = f2bf(f.y); o.z = f2bf(f.z); o.w = f2bf(f.w);
      ((ushort4*)dst)[off] = o;
    } else if (u < 3 * NXv + 4 * NWv) {
      size_t uu = u - 3 * NXv;
      int wsel = (int)(uu / NWv); size_t off = uu % NWv;
      const float* src = wsel == 0 ? wq : wsel == 1 ? wk : wsel == 2 ? wv : wo;
      unsigned short* dst = wsel == 0 ? Wqb : wsel == 1 ? Wkb : wsel == 2 ? Wvb : Wob;
      float4 f = ((const float4*)src)[off];
      ushort4 o; o.x = f2bf(f.x); o.y = f2bf(f.y); o.z = f2bf(f.z); o.w = f2bf(f.w);
      ((ushort4*)dst)[off] = o;
    } else {
      size_t off = u - 3 * NXv - 4 * NWv;
      int4 m = ((const int4*)mask)[off];
      if (m.x == 0 || m.y == 0 || m.z == 0 || m.w == 0) *flagZero = 1;
    }
  }
}

// ============ 128x128 GEMM core: C = A(MxK) * B(NxK)^T, bf16, m97 structure ============
DEV void gemm128(const unsigned short* __restrict__ A, const unsigned short* __restrict__ Bm,
                 unsigned short* Asm, unsigned short* Bsm, f32x4 acc[4][4], int K)
{
  const int t = threadIdx.x;
  const int w = t >> 6, lane = t & 63;
  const int l15 = lane & 15, l4 = lane >> 4;
  const int wm = w >> 1, wn = w & 1;
  const int srow = lane >> 2;
  const int skc  = (lane & 3) * 8;
#pragma unroll
  for (int mi = 0; mi < 4; ++mi)
#pragma unroll
    for (int ni = 0; ni < 4; ++ni) acc[mi][ni] = (f32x4){0.f, 0.f, 0.f, 0.f};

  for (int k0 = 0; k0 < K; k0 += 32) {
    GLDS16(A  + (size_t)(w * 16 + srow) * K + k0 + skc,        Asm + w * 512);
    GLDS16(A  + (size_t)(64 + w * 16 + srow) * K + k0 + skc,   Asm + 2048 + w * 512);
    GLDS16(Bm + (size_t)(w * 16 + srow) * K + k0 + skc,        Bsm + w * 512);
    GLDS16(Bm + (size_t)(64 + w * 16 + srow) * K + k0 + skc,   Bsm + 2048 + w * 512);
    __syncthreads();
    short8 af[4], bf[4];
#pragma unroll
    for (int mi = 0; mi < 4; ++mi)
      af[mi] = *(const short8*)&Asm[(wm * 64 + mi * 16 + l15) * 32 + l4 * 8];
#pragma unroll
    for (int ni = 0; ni < 4; ++ni)
      bf[ni] = *(const short8*)&Bsm[(wn * 64 + ni * 16 + l15) * 32 + l4 * 8];
#pragma unroll
    for (int mi = 0; mi < 4; ++mi)
#pragma unroll
      for (int ni = 0; ni < 4; ++ni)
        acc[mi][ni] = __builtin_amdgcn_mfma_f32_16x16x32_bf16(af[mi], bf[ni], acc[mi][ni], 0, 0, 0);
    __syncthreads();
  }
}

// ============ QKV projection ============
__global__ __launch_bounds__(256) void gemm_qkv(
    const unsigned short* __restrict__ Xq, const unsigned short* __restrict__ Xk,
    const unsigned short* __restrict__ Xv,
    const unsigned short* __restrict__ Wqb, const unsigned short* __restrict__ Wkb,
    const unsigned short* __restrict__ Wvb,
    const float* __restrict__ bq, const float* __restrict__ bk, const float* __restrict__ bv,
    unsigned short* __restrict__ Qh, unsigned short* __restrict__ Kh, unsigned short* __restrict__ Vh)
{
  __shared__ unsigned short Asm[128 * 32], Bsm[128 * 32];
  const int z = blockIdx.z;
  const unsigned short* A  = (z == 0) ? Xq  : (z == 1) ? Xk  : Xv;
  const unsigned short* Bw = (z == 0) ? Wqb : (z == 1) ? Wkb : Wvb;
  const float* bias        = (z == 0) ? bq  : (z == 1) ? bk  : bv;
  unsigned short* Out      = (z == 0) ? Qh  : (z == 1) ? Kh  : Vh;
  const int by = blockIdx.y, bx = blockIdx.x;
  f32x4 acc[4][4];
  gemm128(A + (size_t)by * 128 * Ee, Bw + (size_t)bx * 128 * Ee, Asm, Bsm, acc, Ee);
  const int t = threadIdx.x, w = t >> 6, lane = t & 63, l15 = lane & 15, l4 = lane >> 4;
  const int wm = w >> 1, wn = w & 1;
#pragma unroll
  for (int ni = 0; ni < 4; ++ni) {
    int col = bx * 128 + wn * 64 + ni * 16 + l15;
    float bcol = bias[col];
    int h = col >> 6, hd = col & 63;
#pragma unroll
    for (int mi = 0; mi < 4; ++mi) {
#pragma unroll
      for (int r = 0; r < 4; ++r) {
        int row = by * 128 + wm * 64 + mi * 16 + l4 * 4 + r;
        int b = row >> 11, s = row & 2047;
        Out[(((size_t)(b * Hh + h)) * Ss + s) * HDd + hd] = f2bf(acc[mi][ni][r] + bcol);
      }
    }
  }
}

// ============ output projection ============
__global__ __launch_bounds__(256) void gemm_out(
    const unsigned short* __restrict__ Ob, const unsigned short* __restrict__ Wob,
    const float* __restrict__ bo, float* __restrict__ out)
{
  __shared__ unsigned short Asm[128 * 32], Bsm[128 * 32];
  const int by = blockIdx.y, bx = blockIdx.x;
  f32x4 acc[4][4];
  gemm128(Ob + (size_t)by * 128 * Ee, Wob + (size_t)bx * 128 * Ee, Asm, Bsm, acc, Ee);
  const int t = threadIdx.x, w = t >> 6, lane = t & 63, l15 = lane & 15, l4 = lane >> 4;
  const int wm = w >> 1, wn = w & 1;
#pragma unroll
  for (int ni = 0; ni < 4; ++ni) {
    int col = bx * 128 + wn * 64 + ni * 16 + l15;
    float bcol = bo[col];
#pragma unroll
    for (int mi = 0; mi < 4; ++mi) {
#pragma unroll
      for (int r = 0; r < 4; ++r) {
        int row = by * 128 + wm * 64 + mi * 16 + l4 * 4 + r;
        out[(size_t)row * Ee + col] = acc[mi][ni][r] + bcol;
      }
    }
  }
}

// ============ flash attention v3: 64 q-rows/block, 4 waves = 2 q-groups x 2 KV parities ============
// wave w: q-group g=w>>1 (rows qt*64+g*32..+31), parity p=w&1 (KV tiles it*128+p*64).
// swapped QK^T: lane owns q-row s = lane&31; reg r -> t = (r&3)+8*(r>>2)+4*(lane>>5).
// End: parity partials merged via LDS (reuse K/V buffers).
__global__ __launch_bounds__(256, 4) void attn_kernel(
    const unsigned short* __restrict__ Qh, const unsigned short* __restrict__ Kh,
    const unsigned short* __restrict__ Vh, const int* __restrict__ mask,
    const int* __restrict__ flagZero, unsigned short* __restrict__ Ob)
{
  __shared__ unsigned short Ks[2][64 * 64];   // [parity][t][d], 16B-chunk XOR-swizzled by (t&7)
  __shared__ unsigned short Vt[2][64 * 72];   // [parity] V^T [hd][t], row pad +8 (bank rotate)
  const int bh = blockIdx.y, qt = blockIdx.x;
  const int tid = threadIdx.x, w = tid >> 6, lane = tid & 63;
  const int l31 = lane & 31, hi = lane >> 5;
  const int g = w >> 1, p = w & 1;
  const bool useMask = (*flagZero != 0);
  const size_t bhBase = (size_t)bh * Ss * HDd;
  const int s0 = qt * 64 + g * 32;
  const float SCL = 0.18033688f;   // 0.125 * log2(e)

  // Q fragments (B-operand): Q[s0 + l31][ks*16 + hi*8 + j]
  short8 qf[4];
#pragma unroll
  for (int ks = 0; ks < 4; ++ks)
    qf[ks] = *(const short8*)&Qh[bhBase + (size_t)(s0 + l31) * 64 + ks * 16 + hi * 8];

  f32x16 o0, o1;
#pragma unroll
  for (int r = 0; r < 16; ++r) { o0[r] = 0.f; o1[r] = 0.f; }
  float m_r = -1e30f, l_r = 0.f;

  // K chunk c (0..511) of a tile: LDS row=c>>3, slot=c&7 holds global chunk (c&7)^(row&7)
  const int kr0 = tid >> 3,        kg0 = (tid & 7) ^ (kr0 & 7);
  const int kc1 = tid + 256;
  const int kr1 = kc1 >> 3,        kg1 = (kc1 & 7) ^ (kr1 & 7);

  const int myKt0 = p * 64;        // my tile offset within each 128-pair

  for (int kt2 = 0; kt2 < Tt; kt2 += 128) {
    // ---- stage both parity tiles (K via global_load_lds; V reg-staged transpose) ----
    const unsigned short* va = Vh + bhBase + (size_t)(kt2 + lane) * 64 + w * 16;
    const unsigned short* vb = va + 64 * 64;
    short8 va0 = *(const short8*)va, va1 = *(const short8*)(va + 8);
    short8 vb0 = *(const short8*)vb, vb1 = *(const short8*)(vb + 8);
    GLDS16(Kh + bhBase + (size_t)(kt2 + kr0) * 64 + kg0 * 8,       &Ks[0][0] + w * 512);
    GLDS16(Kh + bhBase + (size_t)(kt2 + kr1) * 64 + kg1 * 8,       &Ks[0][0] + 2048 + w * 512);
    GLDS16(Kh + bhBase + (size_t)(kt2 + 64 + kr0) * 64 + kg0 * 8,  &Ks[1][0] + w * 512);
    GLDS16(Kh + bhBase + (size_t)(kt2 + 64 + kr1) * 64 + kg1 * 8,  &Ks[1][0] + 2048 + w * 512);
#pragma unroll
    for (int k2 = 0; k2 < 8; ++k2) {
      Vt[0][(w * 16 + k2) * 72 + lane]     = (unsigned short)va0[k2];
      Vt[0][(w * 16 + 8 + k2) * 72 + lane] = (unsigned short)va1[k2];
      Vt[1][(w * 16 + k2) * 72 + lane]     = (unsigned short)vb0[k2];
      Vt[1][(w * 16 + 8 + k2) * 72 + lane] = (unsigned short)vb1[k2];
    }
    __syncthreads();

    const int kt = kt2 + myKt0;
    // ---- QK^T ----
    f32x16 p0, p1;
#pragma unroll
    for (int r = 0; r < 16; ++r) { p0[r] = 0.f; p1[r] = 0.f; }
    const unsigned short* Kc = &Ks[p][0];
    __builtin_amdgcn_s_setprio(1);
#pragma unroll
    for (int ks = 0; ks < 4; ++ks) {
      int row0 = l31, row1 = 32 + l31;
      short8 ka0 = *(const short8*)&Kc[row0 * 64 + (((ks * 2 + hi) ^ (row0 & 7)) * 8)];
      short8 ka1 = *(const short8*)&Kc[row1 * 64 + (((ks * 2 + hi) ^ (row1 & 7)) * 8)];
      p0 = __builtin_amdgcn_mfma_f32_32x32x16_bf16(ka0, qf[ks], p0, 0, 0, 0);
      p1 = __builtin_amdgcn_mfma_f32_32x32x16_bf16(ka1, qf[ks], p1, 0, 0, 0);
    }
    __builtin_amdgcn_s_setprio(0);

    if (useMask) {
      int sg = s0 + l31;
#pragma unroll
      for (int r = 0; r < 16; ++r) {
        int tg = kt + (r & 3) + 8 * (r >> 2) + 4 * hi;
        if (mask[(size_t)sg * Tt + tg] == 0)      p0[r] = -1e30f;
        if (mask[(size_t)sg * Tt + tg + 32] == 0) p1[r] = -1e30f;
      }
    }

    // ---- online softmax (tree-shaped reductions; partner = lane^32) ----
    float mx[8];
#pragma unroll
    for (int i = 0; i < 8; ++i)
      mx[i] = fmaxf(fmaxf(p0[2 * i], p0[2 * i + 1]), fmaxf(p1[2 * i], p1[2 * i + 1]));
    mx[0] = fmaxf(mx[0], mx[4]); mx[1] = fmaxf(mx[1], mx[5]);
    mx[2] = fmaxf(mx[2], mx[6]); mx[3] = fmaxf(mx[3], mx[7]);
    float pmax = fmaxf(fmaxf(mx[0], mx[2]), fmaxf(mx[1], mx[3]));
    pmax = fmaxf(pmax, __shfl_xor(pmax, 32));

    if (!__all(pmax - m_r <= 44.0f)) {           // T13 defer-max (P bounded by ~2^8)
      float mnew = fmaxf(m_r, pmax);
      float alpha = EXP2((m_r - mnew) * SCL);    // m_r=-1e30 first tile -> alpha=0
      l_r *= alpha;
#pragma unroll
      for (int r = 0; r < 16; ++r) {
        int sr = (r & 3) + 8 * (r >> 2) + 4 * hi;
        float ar = __shfl(alpha, sr);
        o0[r] *= ar; o1[r] *= ar;
      }
      m_r = mnew;
    }
    float mm = m_r * SCL;
#pragma unroll
    for (int r = 0; r < 16; ++r) { p0[r] = EXP2(fmaf(p0[r], SCL, -mm)); }
#pragma unroll
    for (int r = 0; r < 16; ++r) { p1[r] = EXP2(fmaf(p1[r], SCL, -mm)); }
    float sm[8];
#pragma unroll
    for (int i = 0; i < 8; ++i)
      sm[i] = (p0[2 * i] + p0[2 * i + 1]) + (p1[2 * i] + p1[2 * i + 1]);
    sm[0] += sm[4]; sm[1] += sm[5]; sm[2] += sm[6]; sm[3] += sm[7];
    float ps = (sm[0] + sm[2]) + (sm[1] + sm[3]);
    l_r += ps + __shfl_xor(ps, 32);

    // ---- pack P to PV A-fragments (cvt_pk + permlane32_swap, no LDS) ----
    short8 pa[4];
#define PACKKS(ks, PV)                                                         \
    {                                                                          \
      unsigned a0, a1, b0, b1; const int bse = 8 * ((ks) & 1);                 \
      CVTPK(a0, PV[bse + 0], PV[bse + 1]);                                     \
      CVTPK(a1, PV[bse + 2], PV[bse + 3]);                                     \
      CVTPK(b0, PV[bse + 4], PV[bse + 5]);                                     \
      CVTPK(b1, PV[bse + 6], PV[bse + 7]);                                     \
      PLSWAP(a0, b0); PLSWAP(a1, b1);                                          \
      union { unsigned u[4]; short8 s; } cc;                                   \
      cc.u[0] = a0; cc.u[1] = a1; cc.u[2] = b0; cc.u[3] = b1;                  \
      pa[ks] = cc.s;                                                           \
    }
    PACKKS(0, p0) PACKKS(1, p0) PACKKS(2, p1) PACKKS(3, p1)
#undef PACKKS

    // ---- PV: O += P * V  (B-frag = V^T rows) ----
    const unsigned short* Vc = &Vt[p][0];
    __builtin_amdgcn_s_setprio(1);
#pragma unroll
    for (int ks = 0; ks < 4; ++ks) {
      short8 vf0 = *(const short8*)&Vc[(l31) * 72 + ks * 16 + hi * 8];
      short8 vf1 = *(const short8*)&Vc[(32 + l31) * 72 + ks * 16 + hi * 8];
      o0 = __builtin_amdgcn_mfma_f32_32x32x16_bf16(pa[ks], vf0, o0, 0, 0, 0);
      o1 = __builtin_amdgcn_mfma_f32_32x32x16_bf16(pa[ks], vf1, o1, 0, 0, 0);
    }
    __builtin_amdgcn_s_setprio(0);
    __syncthreads();
  }

  // ---- merge parity partials (reuse dead LDS) ----
  float* Ox = (float*)&Ks[0][0];       // [g][32 rows][64 cols] f32 = 16 KB
  float* Ml = (float*)&Vt[0][0];       // [g][ m(32) | l(32) ]
  if (p == 1) {
#pragma unroll
    for (int r = 0; r < 16; ++r) {
      int sr = (r & 3) + 8 * (r >> 2) + 4 * hi;
      Ox[g * 2048 + sr * 64 + l31]      = o0[r];
      Ox[g * 2048 + sr * 64 + 32 + l31] = o1[r];
    }
    if (hi == 0) { Ml[g * 64 + l31] = m_r; Ml[g * 64 + 32 + l31] = l_r; }
  }
  __syncthreads();
  if (p == 0) {
    const int b = bh >> 4, h = bh & 15;
    float m1v = Ml[g * 64 + l31], l1v = Ml[g * 64 + 32 + l31];
    float mmF = fmaxf(m_r, m1v);
    float f0 = EXP2((m_r - mmF) * SCL);
    float f1 = EXP2((m1v - mmF) * SCL);
    float lt = l_r * f0 + l1v * f1;
    float linv = lt > 0.f ? 1.0f / lt : 0.f;
    float s0f = f0 * linv, s1f = f1 * linv;
#pragma unroll
    for (int r = 0; r < 16; ++r) {
      int sr = (r & 3) + 8 * (r >> 2) + 4 * hi;
      float a = __shfl(s0f, sr);
      float bb = __shfl(s1f, sr);
      size_t rowbase = (size_t)(b * Ss + s0 + sr) * Ee + h * 64;
      Ob[rowbase + l31]      = f2bf(o0[r] * a + Ox[g * 2048 + sr * 64 + l31] * bb);
      Ob[rowbase + 32 + l31] = f2bf(o1[r] * a + Ox[g * 2048 + sr * 64 + 32 + l31] * bb);
    }
  }
}

extern "C" void kernel_launch(void* const* d_in, const int* in_sizes, int n_in,
                              void* d_out, int out_size, void* d_ws, size_t ws_size,
                              hipStream_t stream) {
  const float* q   = (const float*)d_in[0];
  const float* k   = (const float*)d_in[1];
  const float* v   = (const float*)d_in[2];
  const int*  msk  = (const int*)d_in[3];
  const float* Wq  = (const float*)d_in[4];
  const float* bq  = (const float*)d_in[5];
  const float* Wk  = (const float*)d_in[6];
  const float* bk  = (const float*)d_in[7];
  const float* Wv  = (const float*)d_in[8];
  const float* bv  = (const float*)d_in[9];
  const float* Wo  = (const float*)d_in[10];
  const float* bo  = (const float*)d_in[11];
  float* out = (float*)d_out;

  char* ws = (char*)d_ws;
  unsigned short* Xq  = (unsigned short*)(ws + OFF_XQ);
  unsigned short* Xk  = (unsigned short*)(ws + OFF_XK);
  unsigned short* Xv  = (unsigned short*)(ws + OFF_XV);
  unsigned short* Wqb = (unsigned short*)(ws + OFF_WQ);
  unsigned short* Wkb = (unsigned short*)(ws + OFF_WK);
  unsigned short* Wvb = (unsigned short*)(ws + OFF_WV);
  unsigned short* Wob = (unsigned short*)(ws + OFF_WO);
  unsigned short* Qh  = (unsigned short*)(ws + OFF_QH);
  unsigned short* Kh  = (unsigned short*)(ws + OFF_KH);
  unsigned short* Vh  = (unsigned short*)(ws + OFF_VH);
  unsigned short* Ob  = (unsigned short*)(ws + OFF_OB);
  int* flagZero       = (int*)(ws + OFF_FLAG);

  hipMemsetAsync(flagZero, 0, 4, stream);
  prep_kernel<<<4096, 256, 0, stream>>>(q, k, v, Wq, Wk, Wv, Wo, msk,
                                        Xq, Xk, Xv, Wqb, Wkb, Wvb, Wob, flagZero);
  gemm_qkv<<<dim3(8, 32, 3), 256, 0, stream>>>(Xq, Xk, Xv, Wqb, Wkb, Wvb,
                                               bq, bk, bv, Qh, Kh, Vh);
  attn_kernel<<<dim3(32, 32), 256, 0, stream>>>(Qh, Kh, Vh, msk, flagZero, Ob);
  gemm_out<<<dim3(8, 32), 256, 0, stream>>>(Ob, Wob, bo, out);
}